// Round 11
// baseline (190.658 us; speedup 1.0000x reference)
//
#include <hip/hip_runtime.h>
#include <cstdint>
#include <cstddef>

#define DEV __device__ __forceinline__

typedef __bf16 bf16_t;
typedef __bf16 bf16x8 __attribute__((ext_vector_type(8)));
typedef float  f32x4  __attribute__((ext_vector_type(4)));
typedef float  f32x2  __attribute__((ext_vector_type(2)));
typedef unsigned int u32x4 __attribute__((ext_vector_type(4)));

DEV bf16_t f2bf(float x) { return (bf16_t)x; }   // RNE cast

// ---- problem sizes ----
constexpr int R_ = 500, C_ = 512, H_ = 38, W_ = 38, K_ = 20;
constexpr int HID = 4096, FEAT = 4608, MP = 512;  // MP = padded M
constexpr int HW = H_ * W_;                        // 1444

// ---- workspace layout ----
constexpr size_t alup(size_t x) { return (x + 255) & ~(size_t)255; }
constexpr size_t O_FMT  = 0;                                        // fmap transposed [1444][512] f32
constexpr size_t O_RSC  = alup(O_FMT  + (size_t)HW*C_*4);           // rois_sc [500][4] f32
constexpr size_t O_FEAT = alup(O_RSC  + (size_t)R_*4*4);            // feat bf16 [512][4608]
constexpr size_t O_FC6  = alup(O_FEAT + (size_t)MP*FEAT*2);         // fc6 bf16 [512][4096]
constexpr size_t O_FC7  = alup(O_FC6  + (size_t)MP*HID*2);          // fc7 f32 [512][4096]
constexpr size_t O_PC   = alup(O_FC7  + (size_t)MP*HID*4);          // pc [500][20] f32
constexpr size_t O_LD   = alup(O_PC   + (size_t)R_*K_*4);           // logits_d [500][20] f32
constexpr size_t O_AN   = alup(O_LD   + (size_t)R_*K_*4);           // ||fc7[r]||^2 [512] f32
constexpr size_t O_OS   = alup(O_AN   + (size_t)MP*4);              // out_sum [20]
constexpr size_t O_HI   = alup(O_OS   + (size_t)K_*4);              // h_idx [20] int
constexpr size_t O_D    = alup(O_HI   + (size_t)K_*4);              // D [500][20] f32
constexpr size_t O_W8T  = alup(O_D    + (size_t)R_*K_*4);           // W8T [40][4096] f32
constexpr size_t O_W7T  = alup(O_W8T  + (size_t)2*K_*HID*4);        // W7T bf16 [4096][4096]
constexpr size_t O_PART = alup(O_W7T  + (size_t)HID*HID*2);         // split-K partials (4 slices max)
constexpr size_t O_HP   = O_PART;                                   // aliases part (dead by then)
constexpr size_t O_DP   = O_PART + (size_t)4*1024*1024;
constexpr size_t O_W6T  = alup(O_PART + (size_t)4*MP*HID*4);        // W6T bf16 [4096][4608] (gated)
constexpr size_t O_ENDF = O_W6T + (size_t)HID*FEAT*2;

// ---- prep: fmap T (0..735) + W8 T (736..775) + W7->bf16^T (776..4871) + W6->bf16^T (4872..9479) ----
__global__ void __launch_bounds__(256) k_prep(const float* __restrict__ fmap,
                                              float* __restrict__ fmapt,
                                              const float* __restrict__ W8c,
                                              const float* __restrict__ W8d,
                                              float* __restrict__ W8T,
                                              const float* __restrict__ W7,
                                              bf16_t* __restrict__ W7T,
                                              const float* __restrict__ W6,
                                              bf16_t* __restrict__ W6T) {
    int b = blockIdx.x, t = threadIdx.x;
    if (b < 736) {
        __shared__ float tile[32][33];
        int p0 = (b % 46) * 32, c0 = (b / 46) * 32;
        int tx = t & 31, ty = t >> 5;
#pragma unroll
        for (int i = 0; i < 4; ++i) {
            int c = c0 + ty + i*8, p = p0 + tx;
            tile[ty + i*8][tx] = (p < HW) ? fmap[(size_t)c*HW + p] : 0.f;
        }
        __syncthreads();
#pragma unroll
        for (int i = 0; i < 4; ++i) {
            int p = p0 + ty + i*8, c = c0 + tx;
            if (p < HW) fmapt[(size_t)p*C_ + c] = tile[tx][ty + i*8];
        }
    } else if (b < 776) {
        int k = b - 736;                                  // 0..39
        const float* src = (k < K_) ? W8c : W8d;
        int kk = (k < K_) ? k : k - K_;
        for (int i = t; i < HID; i += 256)
            W8T[(size_t)k*HID + i] = src[(size_t)i*K_ + kk];
    } else {
        // transpose+cast 64x64 tile: dst[n][k] = src[k][n]
        const float* src; bf16_t* dst; int k0, n0, dstlen;
        if (b < 776 + 4096) {
            int j = b - 776;                              // W7: [4096][4096]
            src = W7; dst = W7T; dstlen = HID;
            k0 = (j >> 6) * 64; n0 = (j & 63) * 64;
        } else {
            int j = b - (776 + 4096);                     // W6: [4608][4096]
            src = W6; dst = W6T; dstlen = FEAT;
            k0 = (j >> 6) * 64; n0 = (j & 63) * 64;       // j>>6 in [0,72)
        }
        __shared__ float tile[64][65];
#pragma unroll
        for (int i = 0; i < 16; ++i) {
            int idx = t + i*256;
            int kk = idx >> 6, nn = idx & 63;
            tile[kk][nn] = src[(size_t)(k0 + kk)*HID + n0 + nn];
        }
        __syncthreads();
#pragma unroll
        for (int i = 0; i < 8; ++i) {
            int idx = t + i*256;
            int nn = idx >> 5, kw = idx & 31;
            bf16_t a = f2bf(tile[2*kw][nn]), c = f2bf(tile[2*kw + 1][nn]);
            unsigned int u = ((unsigned short*)&a)[0] | ((unsigned int)((unsigned short*)&c)[0] << 16);
            *reinterpret_cast<unsigned int*>(&dst[(size_t)(n0 + nn)*dstlen + k0 + 2*kw]) = u;
        }
    }
}

// ---- ROI max pool, split over (roi, bin): feat[r, c*9 + bin] ----
__global__ void __launch_bounds__(256) k_roipool(const float* __restrict__ fmapt,
                                                 const float* __restrict__ rois,
                                                 bf16_t* __restrict__ feat,
                                                 float* __restrict__ rois_sc) {
    int r = blockIdx.x, bin = blockIdx.y, t = threadIdx.x;
    if (r >= R_) {
        feat[(size_t)r*FEAT + (size_t)t*9       + bin] = (bf16_t)0.f;
        feat[(size_t)r*FEAT + (size_t)(t+256)*9 + bin] = (bf16_t)0.f;
        return;
    }
    int x1 = (int)floorf(rois[r*4+0] * 0.0625f);
    int y1 = (int)floorf(rois[r*4+1] * 0.0625f);
    int x2 = (int)floorf(rois[r*4+2] * 0.0625f);
    int y2 = (int)floorf(rois[r*4+3] * 0.0625f);
    if (bin == 0 && t == 0) {
        rois_sc[r*4+0] = (float)x1; rois_sc[r*4+1] = (float)y1;
        rois_sc[r*4+2] = (float)x2; rois_sc[r*4+3] = (float)y2;
    }
    int Lx = x2 - x1, Ly = y2 - y1;
    int pr = bin / 3, px = bin - pr*3;
    int rs = y1 + (pr*Ly)/3, re = y1 + ((pr+1)*Ly + 2)/3;
    int cs = x1 + (px*Lx)/3, ce = x1 + ((px+1)*Lx + 2)/3;
    float m0 = -3.402823466e38f, m1 = -3.402823466e38f;
    for (int y = rs; y < re; ++y) {
        const float* rowp = fmapt + (size_t)(y*W_)*C_;
        for (int x = cs; x < ce; ++x) {
            const float* p = rowp + (size_t)x*C_;
            m0 = fmaxf(m0, p[t]);
            m1 = fmaxf(m1, p[t + 256]);
        }
    }
    feat[(size_t)r*FEAT + (size_t)t*9       + bin] = f2bf(m0);
    feat[(size_t)r*FEAT + (size_t)(t+256)*9 + bin] = f2bf(m1);
}

// ---- GEMM bt2: both operands bf16 [row][k] via global_load_lds, TRIPLE buffer,
// counted vmcnt(4) (tile t+1's 4 loads/thread stay in flight across the barrier).
// Buffer safety: stage(t+2)->buf[(t+2)%3] issued AFTER this wave's MFMA(t); all
// waves passed barrier(t) => all finished MFMA(t-1) reading buf[(t-1)%3]=(t+2)%3.
__global__ void __launch_bounds__(512, 2)
k_gemm_bt2(const bf16_t* __restrict__ A, const bf16_t* __restrict__ BT,
           float* __restrict__ part, int KDIM, int nts) {
    __shared__ bf16_t Asm[3][128*64];   // 48 KB
    __shared__ bf16_t Bsm[3][128*64];   // 48 KB
    const int t = threadIdx.x;
    const int lane = t & 63, wid = t >> 6;
    const int wr = wid >> 2, wc = wid & 3;              // 2 x 4 wave grid

    const int flat = blockIdx.x + 32*blockIdx.y + 128*blockIdx.z;
    const int q = 16 * gridDim.z;                       // nwg/8
    const int v = (flat & 7) * q + (flat >> 3);
    const int by = v & 3, bx = (v >> 2) & 31, bz = v >> 7;

    const int brow = by * 128, bcol = bx * 128;
    const int kt0 = bz * nts;

    f32x4 acc[4][2] = {};

    auto stage = [&](const bf16_t* base, int kt, bf16_t* lds) {
        const bf16_t* g = base + kt*64;
#pragma unroll
        for (int i = 0; i < 2; ++i) {
            int s = t + i*512;
            int row = s >> 3;
            int kb = (s & 7) ^ ((row >> 1) & 7);        // pre-swizzled source octet
            const bf16_t* src = g + (size_t)row*KDIM + kb*8;
            bf16_t* dst = lds + (size_t)(i*512 + (t & ~63)) * 8;   // wave-uniform base
            __builtin_amdgcn_global_load_lds(
                (const __attribute__((address_space(1))) void*)src,
                (__attribute__((address_space(3))) void*)dst, 16, 0, 0);
        }
    };

    const bf16_t* Abase = A  + (size_t)brow*KDIM;
    const bf16_t* Bbase = BT + (size_t)bcol*KDIM;

    // prologue: tiles 0,1 in flight (8 ops/thread)
    stage(Abase, kt0 + 0, &Asm[0][0]);
    stage(Bbase, kt0 + 0, &Bsm[0][0]);
    stage(Abase, kt0 + 1, &Asm[1][0]);
    stage(Bbase, kt0 + 1, &Bsm[1][0]);

    int cur = 0, nx2 = 2;                               // buf indices: it%3, (it+2)%3
    for (int it = 0; it < nts; ++it) {
        // tile `it` must be landed; tile it+1 (4 newest ops) may stay in flight
        if (it == nts - 1) asm volatile("s_waitcnt vmcnt(0)" ::: "memory");
        else               asm volatile("s_waitcnt vmcnt(4)" ::: "memory");
        __builtin_amdgcn_sched_barrier(0);
        __builtin_amdgcn_s_barrier();
        __builtin_amdgcn_sched_barrier(0);

        const bf16_t* Ac = &Asm[cur][0];
        const bf16_t* Bc = &Bsm[cur][0];
#pragma unroll
        for (int kk = 0; kk < 2; ++kk) {
            const int kb = kk*4 + (lane >> 4);
            bf16x8 af[4], bfr[2];
#pragma unroll
            for (int m = 0; m < 4; ++m) {
                int row = wr*64 + m*16 + (lane & 15);
                af[m] = *reinterpret_cast<const bf16x8*>(
                    Ac + (size_t)(row*8 + (kb ^ ((row >> 1) & 7))) * 8);
            }
#pragma unroll
            for (int n = 0; n < 2; ++n) {
                int nn = wc*32 + n*16 + (lane & 15);
                bfr[n] = *reinterpret_cast<const bf16x8*>(
                    Bc + (size_t)(nn*8 + (kb ^ ((nn >> 1) & 7))) * 8);
            }
#pragma unroll
            for (int m = 0; m < 4; ++m)
#pragma unroll
                for (int n = 0; n < 2; ++n)
                    acc[m][n] = __builtin_amdgcn_mfma_f32_16x16x32_bf16(af[m], bfr[n], acc[m][n], 0, 0, 0);
        }
        if (it + 2 < nts) {                             // stage t+2 (after MFMA, below barrier)
            stage(Abase, kt0 + it + 2, &Asm[nx2][0]);
            stage(Bbase, kt0 + it + 2, &Bsm[nx2][0]);
        }
        cur = (cur == 2) ? 0 : cur + 1;
        nx2 = (nx2 == 2) ? 0 : nx2 + 1;
    }

    float* dst = part + (size_t)bz * MP * HID;
#pragma unroll
    for (int m = 0; m < 4; ++m) {
        int row0 = brow + wr*64 + m*16 + ((lane >> 4) << 2);
#pragma unroll
        for (int n = 0; n < 2; ++n) {
            int col = bcol + wc*32 + n*16 + (lane & 15);
#pragma unroll
            for (int j = 0; j < 4; ++j)
                dst[(size_t)(row0 + j)*HID + col] = acc[m][n][j];
        }
    }
}

// ---- GEMM1 fallback (r10-proven): part[bz] = A(bf16) * B(f32 -> bf16 in-loop) ----
__global__ void __launch_bounds__(512, 4)
k_gemm(const bf16_t* __restrict__ A, const float* __restrict__ B,
       float* __restrict__ part, int KDIM, int nts) {
    __shared__ bf16_t Asm[2][128*64];
    __shared__ bf16_t Bsm[2][128*64];
    const int t = threadIdx.x;
    const int lane = t & 63, wid = t >> 6;
    const int wr = wid >> 2, wc = wid & 3;

    const int flat = blockIdx.x + 32*blockIdx.y + 128*blockIdx.z;
    const int q = 16 * gridDim.z;
    const int v = (flat & 7) * q + (flat >> 3);
    const int by = v & 3, bx = (v >> 2) & 31, bz = v >> 7;

    const int brow = by * 128, bcol = bx * 128;
    const int kt0 = bz * nts;

    f32x4 acc[4][2] = {};
    f32x2 br[8];
    const int n2 = t & 63, kgl = t >> 6;

    auto stage_A = [&](int kt, int buf) {
        const bf16_t* Ag = A + (size_t)brow*KDIM + kt*64;
#pragma unroll
        for (int i = 0; i < 2; ++i) {
            int s = t + i*512;
            int row = s >> 3;
            int kb = (s & 7) ^ ((row >> 1) & 7);
            const bf16_t* src = Ag + (size_t)row*KDIM + kb*8;
            bf16_t* dst = &Asm[buf][(size_t)(i*512 + (t & ~63)) * 8];
            __builtin_amdgcn_global_load_lds(
                (const __attribute__((address_space(1))) void*)src,
                (__attribute__((address_space(3))) void*)dst, 16, 0, 0);
        }
    };
    auto load_B = [&](int kt) {
        const float* src = B + (size_t)(kt*64 + kgl*8)*HID + bcol + 2*n2;
#pragma unroll
        for (int j = 0; j < 8; ++j)
            br[j] = *reinterpret_cast<const f32x2*>(src + (size_t)j*HID);
    };
    auto write_B = [&](int buf) {
        const int sw = n2 & 7;
        bf16x8 v0, v1;
#pragma unroll
        for (int j = 0; j < 8; ++j) { v0[j] = f2bf(br[j].x); v1[j] = f2bf(br[j].y); }
        *reinterpret_cast<u32x4*>(&Bsm[buf][(size_t)((2*n2    )*8 + (kgl ^ sw)) * 8]) = *reinterpret_cast<u32x4*>(&v0);
        *reinterpret_cast<u32x4*>(&Bsm[buf][(size_t)((2*n2 + 1)*8 + (kgl ^ sw)) * 8]) = *reinterpret_cast<u32x4*>(&v1);
    };

    stage_A(kt0, 0);
    load_B(kt0);
    write_B(0);
    __syncthreads();

    for (int it = 0; it < nts; ++it) {
        const int cur = it & 1;
        if (it + 1 < nts) { stage_A(kt0 + it + 1, cur ^ 1); load_B(kt0 + it + 1); }
#pragma unroll
        for (int kk = 0; kk < 2; ++kk) {
            const int kb = kk*4 + (lane >> 4);
            bf16x8 af[4], bfr[2];
#pragma unroll
            for (int m = 0; m < 4; ++m) {
                int row = wr*64 + m*16 + (lane & 15);
                af[m] = *reinterpret_cast<const bf16x8*>(
                    &Asm[cur][(size_t)(row*8 + (kb ^ ((row >> 1) & 7))) * 8]);
            }
#pragma unroll
            for (int n = 0; n < 2; ++n) {
                int nn = wc*32 + n*16 + (lane & 15);
                bfr[n] = *reinterpret_cast<const bf16x8*>(
                    &Bsm[cur][(size_t)(nn*8 + (kb ^ ((nn >> 1) & 7))) * 8]);
            }
#pragma unroll
            for (int m = 0; m < 4; ++m)
#pragma unroll
                for (int n = 0; n < 2; ++n)
                    acc[m][n] = __builtin_amdgcn_mfma_f32_16x16x32_bf16(af[m], bfr[n], acc[m][n], 0, 0, 0);
        }
        if (it + 1 < nts) { write_B(cur ^ 1); __syncthreads(); }
    }

    float* dst = part + (size_t)bz * MP * HID;
#pragma unroll
    for (int m = 0; m < 4; ++m) {
        int row0 = brow + wr*64 + m*16 + ((lane >> 4) << 2);
#pragma unroll
        for (int n = 0; n < 2; ++n) {
            int col = bcol + wc*32 + n*16 + (lane & 15);
#pragma unroll
            for (int j = 0; j < 4; ++j)
                dst[(size_t)(row0 + j)*HID + col] = acc[m][n][j];
        }
    }
}

// ---- split-K reduce + bias; writes bf16 (fc6) or f32 (fc7) ----
__global__ void __launch_bounds__(256) k_reduce(const float* __restrict__ part,
                                                const float* __restrict__ bias,
                                                bf16_t* __restrict__ ob, float* __restrict__ of,
                                                int ksplit) {
    size_t idx = ((size_t)blockIdx.x*256 + threadIdx.x) * 4;
    f32x4 s = *reinterpret_cast<const f32x4*>(part + idx);
    for (int ss = 1; ss < ksplit; ++ss)
        s += *reinterpret_cast<const f32x4*>(part + (size_t)ss*MP*HID + idx);
    int col = (int)(idx & (HID - 1));
    s += *reinterpret_cast<const f32x4*>(bias + col);
    if (ob) {
#pragma unroll
        for (int j = 0; j < 4; ++j) ob[idx + j] = f2bf(s[j]);
    } else {
        *reinterpret_cast<f32x4*>(of + idx) = s;
    }
}

// ---- tiled column-dots: partial[kb][r][o] = fc7[r][kchunk] . Brow_o[kchunk] ----
template<int NOUT, bool SELF>
__global__ void __launch_bounds__(256) k_dotcols(const float* __restrict__ fc7,
        const float* __restrict__ Bmat, const int* __restrict__ bidx,
        float* __restrict__ partial) {
    constexpr int NO = NOUT + (SELF ? 1 : 0);
    constexpr int SLICE = NOUT*16 + 4;
    __shared__ float Bs[8 * SLICE];
    const int rb = blockIdx.x, kb = blockIdx.y, t = threadIdx.x;
    const int k0 = kb * 128;
    for (int i = t; i < NOUT*32; i += 256) {
        int o = i >> 5, c = i & 31;
        const float* src = bidx ? fc7 + (size_t)bidx[o]*HID : Bmat + (size_t)o*HID;
        f32x4 v = *reinterpret_cast<const f32x4*>(src + k0 + c*4);
        *reinterpret_cast<f32x4*>(&Bs[(c >> 2)*SLICE + o*16 + (c & 3)*4]) = v;
    }
    __syncthreads();
    const int lane = t & 63, w = t >> 6;
    const int ri = lane >> 3, kk = lane & 7;
    const int r0 = rb*64 + w*16 + ri*2;
    f32x4 x0[4], x1[4];
    const float* f0 = fc7 + (size_t)r0*HID + k0 + kk*16;
#pragma unroll
    for (int j = 0; j < 4; ++j) {
        x0[j] = *reinterpret_cast<const f32x4*>(f0 + j*4);
        x1[j] = *reinterpret_cast<const f32x4*>(f0 + HID + j*4);
    }
    float acc0[NO], acc1[NO];
#pragma unroll
    for (int o = 0; o < NOUT; ++o) {
        f32x4 s0 = {}, s1 = {};
#pragma unroll
        for (int j = 0; j < 4; ++j) {
            f32x4 wv = *reinterpret_cast<const f32x4*>(&Bs[kk*SLICE + o*16 + j*4]);
            s0 += x0[j] * wv;
            s1 += x1[j] * wv;
        }
        acc0[o] = s0[0]+s0[1]+s0[2]+s0[3];
        acc1[o] = s1[0]+s1[1]+s1[2]+s1[3];
    }
    if (SELF) {
        f32x4 s0 = {}, s1 = {};
#pragma unroll
        for (int j = 0; j < 4; ++j) { s0 += x0[j]*x0[j]; s1 += x1[j]*x1[j]; }
        acc0[NO-1] = s0[0]+s0[1]+s0[2]+s0[3];
        acc1[NO-1] = s1[0]+s1[1]+s1[2]+s1[3];
    }
#pragma unroll
    for (int o = 0; o < NO; ++o) {
#pragma unroll
        for (int m = 1; m < 8; m <<= 1) {
            acc0[o] += __shfl_xor(acc0[o], m, 64);
            acc1[o] += __shfl_xor(acc1[o], m, 64);
        }
    }
    if (kk == 0) {
#pragma unroll
        for (int o = 0; o < NO; ++o) {
            partial[((size_t)kb*MP + r0    )*NO + o] = acc0[o];
            partial[((size_t)kb*MP + r0 + 1)*NO + o] = acc1[o];
        }
    }
}

// ---- heads reduce ----
__global__ void __launch_bounds__(64) k_headred(const float* __restrict__ hpart,
        const float* __restrict__ b8c, const float* __restrict__ b8d,
        float* __restrict__ pc, float* __restrict__ ld, float* __restrict__ An) {
    int r = blockIdx.x, t = threadIdx.x;
    __shared__ float lcs[20];
    if (t < 41) {
        float s = 0.f;
        for (int kb = 0; kb < 32; ++kb) s += hpart[((size_t)kb*MP + r)*41 + t];
        if (t < 20)      lcs[t] = s + b8c[t];
        else if (t < 40) ld[r*K_ + (t-20)] = s + b8d[t-20];
        else             An[r] = s;
    }
    __syncthreads();
    if (t == 0) {
        float mx = lcs[0];
#pragma unroll
        for (int k = 1; k < 20; ++k) mx = fmaxf(mx, lcs[k]);
        float sum = 0.f, e[20];
#pragma unroll
        for (int k = 0; k < 20; ++k) { e[k] = expf(lcs[k] - mx); sum += e[k]; }
        float inv = 1.f / sum;
#pragma unroll
        for (int k = 0; k < 20; ++k) pc[r*K_ + k] = e[k] * inv;
    }
}

// ---- dmat reduce ----
__global__ void __launch_bounds__(64) k_dmatred(const float* __restrict__ dpart,
                                                float* __restrict__ D) {
    int r = blockIdx.x, t = threadIdx.x;
    if (t < 20) {
        float s = 0.f;
        for (int kb = 0; kb < 32; ++kb) s += dpart[((size_t)kb*MP + r)*20 + t];
        D[r*K_ + t] = s;
    }
}

// ---- per-class column softmax, scores, column sum, argmin (stable) ----
__global__ void __launch_bounds__(256) k_pd(const float* __restrict__ ld,
        const float* __restrict__ pc, float* __restrict__ scores,
        float* __restrict__ out_sum, int* __restrict__ h_idx) {
    int k = blockIdx.x, t = threadIdx.x;
    __shared__ float sh[4];
    float m = -3.402823466e38f;
    for (int r = t; r < R_; r += 256) m = fmaxf(m, ld[r*K_ + k]);
    for (int off = 1; off < 64; off <<= 1) m = fmaxf(m, __shfl_xor(m, off, 64));
    if ((t & 63) == 0) sh[t >> 6] = m;
    __syncthreads();
    m = fmaxf(fmaxf(sh[0], sh[1]), fmaxf(sh[2], sh[3]));
    __syncthreads();
    float s = 0.f;
    for (int r = t; r < R_; r += 256) s += expf(ld[r*K_ + k] - m);
    for (int off = 1; off < 64; off <<= 1) s += __shfl_xor(s, off, 64);
    if ((t & 63) == 0) sh[t >> 6] = s;
    __syncthreads();
    s = sh[0] + sh[1] + sh[2] + sh[3];
    float inv = 1.f / s;

    float osum = 0.f, bv = 3.402823466e38f; int bi = 0x7fffffff;
    for (int r = t; r < R_; r += 256) {
        float p  = expf(ld[r*K_ + k] - m) * inv;
        float sc = pc[r*K_ + k] * p;
        scores[r*K_ + k] = sc;
        osum += sc;
        if (sc < bv || (sc == bv && r < bi)) { bv = sc; bi = r; }
    }
    for (int off = 1; off < 64; off <<= 1) osum += __shfl_xor(osum, off, 64);
    for (int off = 1; off < 64; off <<= 1) {
        float v2 = __shfl_xor(bv, off, 64);
        int   i2 = __shfl_xor(bi, off, 64);
        if (v2 < bv || (v2 == bv && i2 < bi)) { bv = v2; bi = i2; }
    }
    __shared__ float so[4], mv[4]; __shared__ int mi[4];
    if ((t & 63) == 0) { so[t >> 6] = osum; mv[t >> 6] = bv; mi[t >> 6] = bi; }
    __syncthreads();
    if (t == 0) {
        out_sum[k] = so[0] + so[1] + so[2] + so[3];
        float v = mv[0]; int i = mi[0];
        for (int w = 1; w < 4; ++w)
            if (mv[w] < v || (mv[w] == v && mi[w] < i)) { v = mv[w]; i = mi[w]; }
        h_idx[k] = i;
    }
}

// ---- final: BCE + spatial regularizer ----
__global__ void __launch_bounds__(256) k_final(const float* __restrict__ out_sum,
        const int* __restrict__ h_idx, const float* __restrict__ label,
        const float* __restrict__ scores, const float* __restrict__ D,
        const float* __restrict__ An, const float* __restrict__ rois_sc,
        float* __restrict__ dout) {
    int t = threadIdx.x;
    __shared__ float bsh[20];
    if (t < 20) {
        float o = out_sum[t], lab = label[t];
        bsh[t] = lab * logf(o) + (1.f - lab) * logf(1.f - o);
    }
    __syncthreads();

    float rp = 0.f;
    for (int i = t; i < R_*K_; i += 256) {
        int r = i / 20, k = i - r*20;
        int h = h_idx[k];
        if (r == h) continue;
        float lab = label[k];
        if (lab == 0.f) continue;
        float s = scores[r*K_ + k];
        const float* rb = rois_sc + r*4;
        const float* hb = rois_sc + h*4;
        float b1x2 = rb[0] + rb[2], b1y2 = rb[1] + rb[3];
        float b2x2 = hb[0] + hb[2], b2y2 = hb[1] + hb[3];
        float iw = fmaxf(fminf(b1x2, b2x2) - fmaxf(rb[0], hb[0]) + 1.f, 0.f);
        float ih = fmaxf(fminf(b1y2, b2y2) - fmaxf(rb[1], hb[1]) + 1.f, 0.f);
        float inter = iw * ih;
        float a1 = (b1x2 - rb[0] + 1.f) * (b1y2 - rb[1] + 1.f);
        float a2 = (b2x2 - hb[0] + 1.f) * (b2y2 - hb[1] + 1.f);
        float iou = inter / (a1 + a2 - inter);
        float mm = (iou > 0.6f) ? 1.f : 0.f;
        float term = mm * (An[r] - 2.f * D[r*K_ + k]) + An[h];
        rp += lab * 0.5f * s * s * term;
    }
    for (int off = 1; off < 64; off <<= 1) rp += __shfl_xor(rp, off, 64);
    __shared__ float rsh[4];
    if ((t & 63) == 0) rsh[t >> 6] = rp;
    __syncthreads();
    if (t == 0) {
        float reg = (rsh[0] + rsh[1] + rsh[2] + rsh[3]) / (float)K_;
        float b = 0.f;
        for (int k = 0; k < 20; ++k) b += bsh[k];
        float bce = -b / (float)K_;
        dout[R_*K_]     = bce + reg;
        dout[R_*K_ + 1] = reg;
    }
}

extern "C" void kernel_launch(void* const* d_in, const int* in_sizes, int n_in,
                              void* d_out, int out_size, void* d_ws, size_t ws_size,
                              hipStream_t stream) {
    const float* fmap  = (const float*)d_in[0];
    const float* rois  = (const float*)d_in[1];
    const float* label = (const float*)d_in[2];
    const float* W6    = (const float*)d_in[3];
    const float* b6    = (const float*)d_in[4];
    const float* W7    = (const float*)d_in[5];
    const float* b7    = (const float*)d_in[6];
    const float* W8c   = (const float*)d_in[7];
    const float* b8c   = (const float*)d_in[8];
    const float* W8d   = (const float*)d_in[9];
    const float* b8d   = (const float*)d_in[10];
    char* ws = (char*)d_ws;
    float* out = (float*)d_out;

    float*  fmapt = (float*)(ws + O_FMT);
    float*  roisc = (float*)(ws + O_RSC);
    bf16_t* feat  = (bf16_t*)(ws + O_FEAT);
    bf16_t* fc6   = (bf16_t*)(ws + O_FC6);
    float*  fc7   = (float*)(ws + O_FC7);
    float*  pc    = (float*)(ws + O_PC);
    float*  ld    = (float*)(ws + O_LD);
    float*  An    = (float*)(ws + O_AN);
    float*  osum  = (float*)(ws + O_OS);
    int*    hidx  = (int*)(ws + O_HI);
    float*  Dm    = (float*)(ws + O_D);
    float*  w8t   = (float*)(ws + O_W8T);
    bf16_t* w7t   = (bf16_t*)(ws + O_W7T);
    float*  part  = (float*)(ws + O_PART);
    float*  hpart = (float*)(ws + O_HP);
    float*  dpart = (float*)(ws + O_DP);
    bf16_t* w6t   = (bf16_t*)(ws + O_W6T);

    const bool full = (ws_size >= O_ENDF);              // room for W6T bf16?
    const int prep_blocks = full ? (776 + 4096 + 4608) : (776 + 4096);

    k_prep   <<<dim3(prep_blocks), dim3(256), 0, stream>>>(fmap, fmapt, W8c, W8d, w8t, W7, w7t, W6, w6t);
    k_roipool<<<dim3(MP, 9),       dim3(256), 0, stream>>>(fmapt, rois, feat, roisc);

    if (full) {
        k_gemm_bt2<<<dim3(32, 4, 2), dim3(512), 0, stream>>>(feat, w6t, part, FEAT, (FEAT/64)/2);
        k_reduce  <<<dim3((MP*HID)/1024), dim3(256), 0, stream>>>(part, b6, fc6, (float*)nullptr, 2);
    } else {
        k_gemm    <<<dim3(32, 4, 4), dim3(512), 0, stream>>>(feat, W6, part, FEAT, (FEAT/64)/4);
        k_reduce  <<<dim3((MP*HID)/1024), dim3(256), 0, stream>>>(part, b6, fc6, (float*)nullptr, 4);
    }

    k_gemm_bt2<<<dim3(32, 4, 2), dim3(512), 0, stream>>>(fc6, w7t, part, HID, (HID/64)/2);
    k_reduce  <<<dim3((MP*HID)/1024), dim3(256), 0, stream>>>(part, b7, (bf16_t*)nullptr, fc7, 2);

    k_dotcols<40, true><<<dim3(MP/64, HID/128), dim3(256), 0, stream>>>(fc7, w8t, (const int*)nullptr, hpart);
    k_headred<<<dim3(R_), dim3(64), 0, stream>>>(hpart, b8c, b8d, pc, ld, An);
    k_pd     <<<dim3(K_), dim3(256), 0, stream>>>(ld, pc, out, osum, hidx);
    k_dotcols<20, false><<<dim3(MP/64, HID/128), dim3(256), 0, stream>>>(fc7, (const float*)nullptr, hidx, dpart);
    k_dmatred<<<dim3(R_), dim3(64), 0, stream>>>(dpart, Dm);
    k_final  <<<dim3(1),  dim3(256), 0, stream>>>(osum, hidx, label, out, Dm, An, roisc, out);
}